// Round 10
// baseline (106.380 us; speedup 1.0000x reference)
//
#include <hip/hip_runtime.h>
#include <stdint.h>

// TopKLayer quirky sparse_hw: per row (3136 elems), t = spatial index of the
// k-th largest |x| (k=313, ties ascending index); keep the t smallest-|x|
// elements (stable). PERSISTENT 4-ROW BLOCKS, software-pipelined: row r+1's
// global loads issued early and its histogram built (into the other of two
// LDS hist buffers) during row r's select phases. Barriers are raw s_barrier
// + lgkmcnt(0) only (no vmcnt drain -> loads fly across barriers). Row in
// registers; register-resident CDF; wave0-local candidate finish.

#define HW    3136
#define NW4   784        // HW/4
#define NT    256
#define ROWS  4
#define KSEL  313u
#define CAP   320u       // candidate bin capacity (stat max ~190)
#define CAP2  64u        // tie-set capacity
#define O_CAND 0         // regions inside a hist buffer (dead after CDF pull)
#define O_HC   384
#define O_TINY 704
#define M31   0x7fffffffu
#define SENT  0xFFFFFFFFu

// LDS-only barrier: order LDS ops, leave global loads in flight (T4 pattern).
__device__ __forceinline__ void bar_lds() {
    asm volatile("s_waitcnt lgkmcnt(0)" ::: "memory");
    __builtin_amdgcn_s_barrier();
    asm volatile("" ::: "memory");
}

__device__ __forceinline__ unsigned wscan_incl(unsigned v) {
    const int lane = threadIdx.x & 63;
#pragma unroll
    for (int d = 1; d < 64; d <<= 1) {
        unsigned o = __shfl_up(v, d, 64);
        if (lane >= d) v += o;
    }
    return v;
}

__device__ __forceinline__ unsigned bcast_first(unsigned flag, unsigned val) {
    unsigned long long bal = __ballot(flag != 0);
    if (!bal) return 0u;
    return __shfl(val, __ffsll(bal) - 1, 64);
}

// One-wave finish: subhist over compacted candidates, locate, tie-rank.
// Reads br[1]=m1, br[3]=cnt. Writes br[2] UNCONDITIONALLY (SENT -> fallback).
template <bool fromTop>
__device__ void wave_finish(unsigned* hr, unsigned* br) {
    const int lane = threadIdx.x & 63;
    const unsigned cnt = br[3];
    const unsigned m1  = br[1];
    unsigned* cand = hr + O_CAND;
    unsigned* hc   = hr + O_HC;
    unsigned* tiny = hr + O_TINY;
    if (cnt > CAP) { if (lane == 0) br[2] = (m1 == 0) ? 0u : SENT; return; }
    for (unsigned i = lane; i < cnt; i += 64) atomicAdd(&hc[cand[i] >> 24], 1u);
    unsigned hh[4];
#pragma unroll
    for (int i = 0; i < 4; ++i) hh[i] = hc[4 * lane + i];
    const unsigned s4 = hh[0] + hh[1] + hh[2] + hh[3];
    unsigned run2 = wscan_incl(s4) - s4;
    unsigned packed2 = 0;
#pragma unroll
    for (int i = 0; i < 4; ++i) {
        if (fromTop) {
            const unsigned suf = cnt - run2 - hh[i];
            if (suf < m1 && m1 <= suf + hh[i])
                packed2 = ((unsigned)(4 * lane + i) << 16) | (m1 - suf);
        } else {
            if (run2 < m1 && m1 <= run2 + hh[i])
                packed2 = ((unsigned)(4 * lane + i) << 16) | (m1 - run2);
        }
        run2 += hh[i];
    }
    packed2 = bcast_first(packed2, packed2);
    if (packed2 == 0) { if (lane == 0) br[2] = 0u; return; }  // m1==0 sentinel
    const unsigned b2 = packed2 >> 16;
    const unsigned m2 = packed2 & 0xFFFFu;
    unsigned tc = 0;
    for (unsigned i = lane; i < cnt; i += 64) tc += ((cand[i] >> 24) == b2);
    const unsigned tincl = wscan_incl(tc);
    const unsigned c2 = __shfl((int)tincl, 63, 64);
    if (c2 > CAP2) { if (lane == 0) br[2] = SENT; return; }
    unsigned tpos = tincl - tc;
    for (unsigned i = lane; i < cnt; i += 64) {
        const unsigned cw = cand[i];
        if ((cw >> 24) == b2) tiny[tpos++] = cw;
    }
    unsigned hitf = 0, resv = 0;
    if ((unsigned)lane < c2) {
        const unsigned ci = tiny[lane];
        const unsigned di = fromTop ? (ci ^ 0xFFFu) : ci;
        unsigned r = 1;
        for (unsigned j = 0; j < c2; ++j) {
            const unsigned dj = fromTop ? (tiny[j] ^ 0xFFFu) : tiny[j];
            if (fromTop ? (dj > di) : (dj < di)) r++;
        }
        if (r == m2) { hitf = 1; resv = ci; }
    }
    resv = bcast_first(hitf, resv);
    if (lane == 0) br[2] = resv;
}

// Pathological fallback: bin-filtered counting rank over global row.
template <bool fromTop>
__device__ void block_fallback(const unsigned* __restrict__ gx, unsigned* br) {
    const unsigned b0 = br[0], m1 = br[1];
    const int t = threadIdx.x;
    for (int j = t; j < HW; j += NT) {
        const unsigned k = gx[j] & M31;
        if ((k >> 20) != b0) continue;
        unsigned Ci = ((k & 0xFFFFFu) << 12) | (unsigned)j;
        if (fromTop) Ci ^= 0xFFFu;
        unsigned r = 1;
        for (int j2 = 0; j2 < HW; ++j2) {
            const unsigned k2 = gx[j2] & M31;
            if ((k2 >> 20) != b0) continue;
            unsigned Cj = ((k2 & 0xFFFFFu) << 12) | (unsigned)j2;
            if (fromTop) Cj ^= 0xFFFu;
            if (fromTop ? (Cj > Ci) : (Cj < Ci)) r++;
        }
        if (r == m1) br[2] = ((k & 0xFFFFFu) << 12) | (unsigned)j;
    }
}

extern "C" __global__ void __launch_bounds__(NT)
topk_kernel(const float* __restrict__ x, float* __restrict__ out) {
    __shared__ unsigned H[2][2048];   // double-buffered hist -> cand/hc/tiny
    __shared__ unsigned s_warp[4];
    __shared__ unsigned s_b[4];       // [0]=bin [1]=m1 [2]=result [3]=counter

    const int t = threadIdx.x;
    const int lane = t & 63;
    const int wid = t >> 6;
    const bool has3 = (t < NW4 - 3 * NT);   // t < 16
    const size_t row0 = (size_t)blockIdx.x * ROWS;
    const uint4 z4 = make_uint4(0u, 0u, 0u, 0u);

    auto hist_row = [&](const uint4* v, unsigned* Hd) {
#pragma unroll
        for (int i = 0; i < 4; ++i) {
            if (i == 3 && !has3) break;
            atomicAdd(&Hd[(v[i].x & M31) >> 20], 1u);
            atomicAdd(&Hd[(v[i].y & M31) >> 20], 1u);
            atomicAdd(&Hd[(v[i].z & M31) >> 20], 1u);
            atomicAdd(&Hd[(v[i].w & M31) >> 20], 1u);
        }
    };
    auto compact = [&](const uint4* v, unsigned b0, unsigned* cand) {
#pragma unroll
        for (int i = 0; i < 4; ++i) {
            if (i == 3 && !has3) break;
            const unsigned i0 = 4u * (unsigned)(t + i * NT);
            unsigned k, p;
            k = v[i].x & M31; if ((k >> 20) == b0) { p = atomicAdd(&s_b[3], 1u); if (p < CAP) cand[p] = ((k & 0xFFFFFu) << 12) | i0; }
            k = v[i].y & M31; if ((k >> 20) == b0) { p = atomicAdd(&s_b[3], 1u); if (p < CAP) cand[p] = ((k & 0xFFFFFu) << 12) | (i0 + 1u); }
            k = v[i].z & M31; if ((k >> 20) == b0) { p = atomicAdd(&s_b[3], 1u); if (p < CAP) cand[p] = ((k & 0xFFFFFu) << 12) | (i0 + 2u); }
            k = v[i].w & M31; if ((k >> 20) == b0) { p = atomicAdd(&s_b[3], 1u); if (p < CAP) cand[p] = ((k & 0xFFFFFu) << 12) | (i0 + 3u); }
        }
    };

    // ---- prologue: clear both buffers, load row0, hist row0 -> H[0] ----
    uint4 va[4], vb[4];
    {
        ((uint4*)H[0])[t] = z4; ((uint4*)H[0])[t + NT] = z4;
        ((uint4*)H[1])[t] = z4; ((uint4*)H[1])[t + NT] = z4;
        const uint4* xin = (const uint4*)(x + row0 * HW);
#pragma unroll
        for (int i = 0; i < 3; ++i) va[i] = xin[t + i * NT];
        va[3] = has3 ? xin[t + 3 * NT] : z4;
    }
    bar_lds();
    hist_row(va, H[0]);
    bar_lds();

    for (int r = 0; r < ROWS; ++r) {
        const int buf = r & 1;
        unsigned* Hb = H[buf];
        unsigned* Hn = H[buf ^ 1];
        const unsigned* __restrict__ gx = (const unsigned*)(x + (row0 + r) * HW);
        uint4* __restrict__ xo = (uint4*)(out + (row0 + r) * HW);

        // issue next row's loads (consumed 2 phases later; no vmcnt drain)
        if (r < ROWS - 1) {
            const uint4* xin = (const uint4*)(x + (row0 + r + 1) * HW);
#pragma unroll
            for (int i = 0; i < 3; ++i) vb[i] = xin[t + i * NT];
            vb[3] = has3 ? xin[t + 3 * NT] : z4;
        }

        // Phase A: CDF pull from Hb -> regs; clear Hn; publish wave sums
        const uint4 ha = ((const uint4*)Hb)[2 * t];
        const uint4 hb2 = ((const uint4*)Hb)[2 * t + 1];
        ((uint4*)Hn)[t] = z4; ((uint4*)Hn)[t + NT] = z4;
        unsigned c[8] = {ha.x, ha.y, ha.z, ha.w, hb2.x, hb2.y, hb2.z, hb2.w};
        unsigned ssum = 0;
#pragma unroll
        for (int i = 0; i < 8; ++i) ssum += c[i];
        const unsigned Si = wscan_incl(ssum);
        if (lane == 63) s_warp[wid] = Si;
        bar_lds();

        // Phase B: base; locate A (register CDF); zero counter; clear hc
        unsigned cross = 0;
        for (int w2 = 0; w2 < wid; ++w2) cross += s_warp[w2];
        const unsigned base = cross + Si - ssum;   // excl CDF of bin 8t
        {
            unsigned run = base;
#pragma unroll
            for (int i = 0; i < 8; ++i) {
                const unsigned suf = HW - run - c[i];
                if (suf < KSEL && KSEL <= suf + c[i]) {
                    s_b[0] = 8u * (unsigned)t + (unsigned)i;
                    s_b[1] = KSEL - suf;
                }
                run += c[i];
            }
        }
        if (t == 0) s_b[3] = 0;
        Hb[O_HC + t] = 0;
        bar_lds();

        // Phase C: compact A from regs + build NEXT row's histogram into Hn
        const unsigned b0A = s_b[0];
        compact(va, b0A, Hb + O_CAND);
        if (r < ROWS - 1) hist_row(vb, Hn);
        bar_lds();

        // Phase D: wave0 finish A
        if (wid == 0) wave_finish<true>(Hb, s_b);
        bar_lds();

        unsigned compA = s_b[2];
        if (compA == SENT) { block_fallback<true>(gx, s_b); __syncthreads(); compA = s_b[2]; }
        const unsigned tIdx = compA & 0xFFFu;

        // Phase E: locate B (register CDF); zero counter; clear hc
        {
            unsigned run = base;
#pragma unroll
            for (int i = 0; i < 8; ++i) {
                if (run < tIdx && tIdx <= run + c[i]) {
                    s_b[0] = 8u * (unsigned)t + (unsigned)i;
                    s_b[1] = tIdx - run;
                }
                run += c[i];
            }
        }
        if (t == 0) {
            s_b[3] = 0;
            if (tIdx == 0) { s_b[0] = 0; s_b[1] = 0; }   // keep-nothing sentinel
        }
        Hb[O_HC + t] = 0;
        bar_lds();

        // Phase F: compact B
        const unsigned b0B = s_b[0];
        compact(va, b0B, Hb + O_CAND);
        bar_lds();

        // Phase G: wave0 finish B
        if (wid == 0) wave_finish<false>(Hb, s_b);
        bar_lds();

        unsigned compB = s_b[2];
        if (compB == SENT) { block_fallback<false>(gx, s_b); __syncthreads(); compB = s_b[2]; }
        const unsigned KB = (b0B << 20) | (compB >> 12);
        const unsigned eB = compB & 0xFFFu;

        // Phase H: mask + store from regs; rotate vb -> va  (no barrier: next
        // Phase A clears Hb [last read Phase G, barrier-covered] and reads Hn
        // [written Phase C, barrier-covered])
#pragma unroll
        for (int i = 0; i < 4; ++i) {
            if (i == 3 && !has3) break;
            const unsigned i0 = 4u * (unsigned)(t + i * NT);
            uint4 o = va[i];
            unsigned k;
            k = o.x & M31; if (!(k < KB || (k == KB && i0      <= eB))) o.x = 0u;
            k = o.y & M31; if (!(k < KB || (k == KB && i0 + 1u <= eB))) o.y = 0u;
            k = o.z & M31; if (!(k < KB || (k == KB && i0 + 2u <= eB))) o.z = 0u;
            k = o.w & M31; if (!(k < KB || (k == KB && i0 + 3u <= eB))) o.w = 0u;
            xo[t + i * NT] = o;
        }
        if (r < ROWS - 1) {
#pragma unroll
            for (int i = 0; i < 4; ++i) va[i] = vb[i];
        }
    }
}

extern "C" void kernel_launch(void* const* d_in, const int* in_sizes, int n_in,
                              void* d_out, int out_size, void* d_ws, size_t ws_size,
                              hipStream_t stream) {
    const float* x = (const float*)d_in[0];
    float* out = (float*)d_out;
    const int rows = in_sizes[0] / HW;          // 8192
    topk_kernel<<<dim3(rows / ROWS), dim3(NT), 0, stream>>>(x, out);
}

// Round 11
// 83.062 us; speedup vs baseline: 1.2807x; 1.2807x over previous
//
#include <hip/hip_runtime.h>
#include <stdint.h>

// TopKLayer quirky sparse_hw: per row (3136 elems), t = spatial index of the
// k-th largest |x| (k=313, ties ascending index); keep the t smallest-|x|
// elements (stable). 128-THREAD BLOCK PER ROW, minimal footprint: row is
// STREAMED from global in each pass (hist/compactA/compactB/mask), LDS is one
// 1024-word packed-u16 2048-bin histogram (reused for cand/hc/tiny), VGPR
// pinned <=64 so 16 blocks/CU co-reside (16 independent row-chains per CU).

#define HW    3136
#define NT    128
#define KSEL  313u
#define CAP   320u       // candidate bin capacity (stat max ~190)
#define CAP2  64u        // tie-set capacity
#define O_CAND 0         // overlay regions in s_h (hist dead after CDF pull)
#define O_HC   384
#define O_TINY 704
#define M31   0x7fffffffu
#define SENT  0xFFFFFFFFu

__device__ __forceinline__ unsigned wscan_incl(unsigned v) {
    const int lane = threadIdx.x & 63;
#pragma unroll
    for (int d = 1; d < 64; d <<= 1) {
        unsigned o = __shfl_up(v, d, 64);
        if (lane >= d) v += o;
    }
    return v;
}

__device__ __forceinline__ unsigned bcast_first(unsigned flag, unsigned val) {
    unsigned long long bal = __ballot(flag != 0);
    if (!bal) return 0u;
    return __shfl(val, __ffsll(bal) - 1, 64);
}

// packed u16 histogram: adjacent bins share one word (word = bin>>1)
__device__ __forceinline__ void hadd(unsigned* h, unsigned b) {
    atomicAdd(&h[b >> 1], (b & 1) ? 0x10000u : 1u);
}

// One-wave finish: subhist over compacted candidates, locate, tie-rank.
// Reads br[1]=m1, br[3]=cnt. Writes br[2] UNCONDITIONALLY (SENT -> fallback).
template <bool fromTop>
__device__ void wave_finish(unsigned* hr, unsigned* br) {
    const int lane = threadIdx.x & 63;
    const unsigned cnt = br[3];
    const unsigned m1  = br[1];
    unsigned* cand = hr + O_CAND;
    unsigned* hc   = hr + O_HC;
    unsigned* tiny = hr + O_TINY;
    if (cnt > CAP) { if (lane == 0) br[2] = (m1 == 0) ? 0u : SENT; return; }
    for (unsigned i = lane; i < cnt; i += 64) atomicAdd(&hc[cand[i] >> 24], 1u);
    unsigned hh[4];
#pragma unroll
    for (int i = 0; i < 4; ++i) hh[i] = hc[4 * lane + i];
    const unsigned s4 = hh[0] + hh[1] + hh[2] + hh[3];
    unsigned run2 = wscan_incl(s4) - s4;
    unsigned packed2 = 0;
#pragma unroll
    for (int i = 0; i < 4; ++i) {
        if (fromTop) {
            const unsigned suf = cnt - run2 - hh[i];
            if (suf < m1 && m1 <= suf + hh[i])
                packed2 = ((unsigned)(4 * lane + i) << 16) | (m1 - suf);
        } else {
            if (run2 < m1 && m1 <= run2 + hh[i])
                packed2 = ((unsigned)(4 * lane + i) << 16) | (m1 - run2);
        }
        run2 += hh[i];
    }
    packed2 = bcast_first(packed2, packed2);
    if (packed2 == 0) { if (lane == 0) br[2] = 0u; return; }  // m1==0 sentinel
    const unsigned b2 = packed2 >> 16;
    const unsigned m2 = packed2 & 0xFFFFu;
    unsigned tc = 0;
    for (unsigned i = lane; i < cnt; i += 64) tc += ((cand[i] >> 24) == b2);
    const unsigned tincl = wscan_incl(tc);
    const unsigned c2 = __shfl((int)tincl, 63, 64);
    if (c2 > CAP2) { if (lane == 0) br[2] = SENT; return; }
    unsigned tpos = tincl - tc;
    for (unsigned i = lane; i < cnt; i += 64) {
        const unsigned cw = cand[i];
        if ((cw >> 24) == b2) tiny[tpos++] = cw;
    }
    unsigned hitf = 0, resv = 0;
    if ((unsigned)lane < c2) {
        const unsigned ci = tiny[lane];
        const unsigned di = fromTop ? (ci ^ 0xFFFu) : ci;
        unsigned r = 1;
        for (unsigned j = 0; j < c2; ++j) {
            const unsigned dj = fromTop ? (tiny[j] ^ 0xFFFu) : tiny[j];
            if (fromTop ? (dj > di) : (dj < di)) r++;
        }
        if (r == m2) { hitf = 1; resv = ci; }
    }
    resv = bcast_first(hitf, resv);
    if (lane == 0) br[2] = resv;
}

// Pathological fallback: bin-filtered counting rank over global row.
template <bool fromTop>
__device__ void block_fallback(const unsigned* __restrict__ gx, unsigned* br) {
    const unsigned b0 = br[0], m1 = br[1];
    const int t = threadIdx.x;
    for (int j = t; j < HW; j += NT) {
        const unsigned k = gx[j] & M31;
        if ((k >> 20) != b0) continue;
        unsigned Ci = ((k & 0xFFFFFu) << 12) | (unsigned)j;
        if (fromTop) Ci ^= 0xFFFu;
        unsigned r = 1;
        for (int j2 = 0; j2 < HW; ++j2) {
            const unsigned k2 = gx[j2] & M31;
            if ((k2 >> 20) != b0) continue;
            unsigned Cj = ((k2 & 0xFFFFFu) << 12) | (unsigned)j2;
            if (fromTop) Cj ^= 0xFFFu;
            if (fromTop ? (Cj > Ci) : (Cj < Ci)) r++;
        }
        if (r == m1) br[2] = ((k & 0xFFFFFu) << 12) | (unsigned)j;
    }
}

extern "C" __global__ void __launch_bounds__(NT, 8)
topk_kernel(const float* __restrict__ x, float* __restrict__ out) {
    __shared__ unsigned s_h[1024];   // 4096 B: packed hist -> cand/hc/tiny
    __shared__ unsigned s_warp[2];
    __shared__ unsigned s_b[4];      // [0]=bin [1]=m1 [2]=result [3]=counter

    const int t = threadIdx.x;
    const int lane = t & 63;
    const int wid = t >> 6;
    const size_t row = blockIdx.x;
    const uint4* __restrict__ xin = (const uint4*)(x + row * HW);
    uint4* __restrict__ xo = (uint4*)(out + row * HW);
    const unsigned* __restrict__ gx = (const unsigned*)xin;

    // P0: clear hist
#pragma unroll
    for (int i = t; i < 1024; i += NT) s_h[i] = 0;
    __syncthreads();

    // P1: stream row, build 2048-bin packed-u16 histogram (abs bits 30:20)
    {
#pragma unroll 2
        for (int i = 0; i < 6; ++i) {
            const uint4 v = xin[t + NT * i];
            hadd(s_h, (v.x & M31) >> 20); hadd(s_h, (v.y & M31) >> 20);
            hadd(s_h, (v.z & M31) >> 20); hadd(s_h, (v.w & M31) >> 20);
        }
        if (t < 16) {
            const uint4 v = xin[t + 768];
            hadd(s_h, (v.x & M31) >> 20); hadd(s_h, (v.y & M31) >> 20);
            hadd(s_h, (v.z & M31) >> 20); hadd(s_h, (v.w & M31) >> 20);
        }
    }
    __syncthreads();

    // P2: pull packed counts (thread t owns bins 16t..16t+15); wave sums
    const uint4 w0 = ((const uint4*)s_h)[2 * t];
    const uint4 w1 = ((const uint4*)s_h)[2 * t + 1];
    unsigned cpk[8] = {w0.x, w0.y, w0.z, w0.w, w1.x, w1.y, w1.z, w1.w};
    unsigned ssum = 0;
#pragma unroll
    for (int j = 0; j < 8; ++j) ssum += (cpk[j] & 0xFFFFu) + (cpk[j] >> 16);
    const unsigned Si = wscan_incl(ssum);
    if (lane == 63) s_warp[wid] = Si;
    __syncthreads();

    // P3: base (excl CDF of bin 16t); locate A; zero counter; clear hc
    const unsigned base = Si - ssum + (wid ? s_warp[0] : 0u);
    {
        unsigned run = base;
#pragma unroll
        for (int j = 0; j < 8; ++j) {
            const unsigned lo = cpk[j] & 0xFFFFu, hi = cpk[j] >> 16;
            unsigned suf = HW - run - lo;
            if (suf < KSEL && KSEL <= suf + lo) { s_b[0] = 16u * t + 2u * j; s_b[1] = KSEL - suf; }
            run += lo;
            suf = HW - run - hi;
            if (suf < KSEL && KSEL <= suf + hi) { s_b[0] = 16u * t + 2u * j + 1u; s_b[1] = KSEL - suf; }
            run += hi;
        }
    }
    if (t == 0) s_b[3] = 0;
    s_h[O_HC + t] = 0; s_h[O_HC + t + NT] = 0;
    __syncthreads();

    // P4: compact A (stream row again)
    {
        const unsigned b0 = s_b[0];
        auto cput = [&](unsigned wv, unsigned idx) {
            const unsigned k = wv & M31;
            if ((k >> 20) == b0) {
                const unsigned p = atomicAdd(&s_b[3], 1u);
                if (p < CAP) s_h[O_CAND + p] = ((k & 0xFFFFFu) << 12) | idx;
            }
        };
#pragma unroll 2
        for (int i = 0; i < 6; ++i) {
            const uint4 v = xin[t + NT * i];
            const unsigned i0 = 4u * (unsigned)(t + NT * i);
            cput(v.x, i0); cput(v.y, i0 + 1u); cput(v.z, i0 + 2u); cput(v.w, i0 + 3u);
        }
        if (t < 16) {
            const uint4 v = xin[t + 768];
            const unsigned i0 = 4u * (unsigned)(t + 768);
            cput(v.x, i0); cput(v.y, i0 + 1u); cput(v.z, i0 + 2u); cput(v.w, i0 + 3u);
        }
    }
    __syncthreads();

    // P5: wave0 finish A
    if (wid == 0) wave_finish<true>(s_h, s_b);
    __syncthreads();

    unsigned compA = s_b[2];
    if (compA == SENT) { block_fallback<true>(gx, s_b); __syncthreads(); compA = s_b[2]; }
    const unsigned tIdx = compA & 0xFFFu;

    // P6: locate B; zero counter; clear hc; keep-nothing sentinel
    {
        unsigned run = base;
#pragma unroll
        for (int j = 0; j < 8; ++j) {
            const unsigned lo = cpk[j] & 0xFFFFu, hi = cpk[j] >> 16;
            if (run < tIdx && tIdx <= run + lo) { s_b[0] = 16u * t + 2u * j; s_b[1] = tIdx - run; }
            run += lo;
            if (run < tIdx && tIdx <= run + hi) { s_b[0] = 16u * t + 2u * j + 1u; s_b[1] = tIdx - run; }
            run += hi;
        }
    }
    if (t == 0) {
        s_b[3] = 0;
        if (tIdx == 0) { s_b[0] = 0; s_b[1] = 0; }   // keep-nothing (benign)
    }
    s_h[O_HC + t] = 0; s_h[O_HC + t + NT] = 0;
    __syncthreads();

    // P7: compact B (stream row again)
    const unsigned b0B = s_b[0];
    {
        auto cput = [&](unsigned wv, unsigned idx) {
            const unsigned k = wv & M31;
            if ((k >> 20) == b0B) {
                const unsigned p = atomicAdd(&s_b[3], 1u);
                if (p < CAP) s_h[O_CAND + p] = ((k & 0xFFFFFu) << 12) | idx;
            }
        };
#pragma unroll 2
        for (int i = 0; i < 6; ++i) {
            const uint4 v = xin[t + NT * i];
            const unsigned i0 = 4u * (unsigned)(t + NT * i);
            cput(v.x, i0); cput(v.y, i0 + 1u); cput(v.z, i0 + 2u); cput(v.w, i0 + 3u);
        }
        if (t < 16) {
            const uint4 v = xin[t + 768];
            const unsigned i0 = 4u * (unsigned)(t + 768);
            cput(v.x, i0); cput(v.y, i0 + 1u); cput(v.z, i0 + 2u); cput(v.w, i0 + 3u);
        }
    }
    __syncthreads();

    // P8: wave0 finish B
    if (wid == 0) wave_finish<false>(s_h, s_b);
    __syncthreads();

    unsigned compB = s_b[2];
    if (compB == SENT) { block_fallback<false>(gx, s_b); __syncthreads(); compB = s_b[2]; }
    const unsigned KB = (b0B << 20) | (compB >> 12);
    const unsigned eB = compB & 0xFFFu;

    // P9: stream row once more, mask + store
    {
        auto msk = [&](unsigned wv, unsigned idx) -> unsigned {
            const unsigned k = wv & M31;
            return (k < KB || (k == KB && idx <= eB)) ? wv : 0u;
        };
#pragma unroll 2
        for (int i = 0; i < 6; ++i) {
            uint4 v = xin[t + NT * i];
            const unsigned i0 = 4u * (unsigned)(t + NT * i);
            v.x = msk(v.x, i0); v.y = msk(v.y, i0 + 1u);
            v.z = msk(v.z, i0 + 2u); v.w = msk(v.w, i0 + 3u);
            xo[t + NT * i] = v;
        }
        if (t < 16) {
            uint4 v = xin[t + 768];
            const unsigned i0 = 4u * (unsigned)(t + 768);
            v.x = msk(v.x, i0); v.y = msk(v.y, i0 + 1u);
            v.z = msk(v.z, i0 + 2u); v.w = msk(v.w, i0 + 3u);
            xo[t + 768] = v;
        }
    }
}

extern "C" void kernel_launch(void* const* d_in, const int* in_sizes, int n_in,
                              void* d_out, int out_size, void* d_ws, size_t ws_size,
                              hipStream_t stream) {
    const float* x = (const float*)d_in[0];
    float* out = (float*)d_out;
    const int rows = in_sizes[0] / HW;          // 8192
    topk_kernel<<<dim3(rows), dim3(NT), 0, stream>>>(x, out);
}

// Round 12
// 59.612 us; speedup vs baseline: 1.7845x; 1.3934x over previous
//
#include <hip/hip_runtime.h>
#include <stdint.h>

// TopKLayer quirky sparse_hw: per row (3136 elems), t = spatial index of the
// k-th largest |x| (k=313, ties ascending index); keep the t smallest-|x|
// elements (stable). 128-THREAD BLOCK PER ROW: row pinned in registers via
// asm keep-alive fence (no remat re-loads -> no L2/HBM re-streams), 4.2 KB
// LDS (packed-u16 2048-bin hist reused as cand/hc/tiny), VGPR capped by
// __launch_bounds__(128,6) -> ~12 resident blocks/CU (3x R7's concurrency).

#define HW    3136
#define NT    128
#define KSEL  313u
#define CAP   320u       // candidate bin capacity (stat max ~190)
#define CAP2  64u        // tie-set capacity
#define O_CAND 0         // overlay regions in s_h (hist dead after CDF pull)
#define O_HC   384
#define O_TINY 704
#define M31   0x7fffffffu
#define SENT  0xFFFFFFFFu

__device__ __forceinline__ unsigned wscan_incl(unsigned v) {
    const int lane = threadIdx.x & 63;
#pragma unroll
    for (int d = 1; d < 64; d <<= 1) {
        unsigned o = __shfl_up(v, d, 64);
        if (lane >= d) v += o;
    }
    return v;
}

__device__ __forceinline__ unsigned bcast_first(unsigned flag, unsigned val) {
    unsigned long long bal = __ballot(flag != 0);
    if (!bal) return 0u;
    return __shfl(val, __ffsll(bal) - 1, 64);
}

// packed u16 histogram: adjacent bins share one word (word = bin>>1)
__device__ __forceinline__ void hadd(unsigned* h, unsigned b) {
    atomicAdd(&h[b >> 1], (b & 1) ? 0x10000u : 1u);
}

// One-wave finish: subhist over compacted candidates, locate, tie-rank.
// Reads br[1]=m1, br[3]=cnt. Writes br[2] UNCONDITIONALLY (SENT -> fallback).
template <bool fromTop>
__device__ void wave_finish(unsigned* hr, unsigned* br) {
    const int lane = threadIdx.x & 63;
    const unsigned cnt = br[3];
    const unsigned m1  = br[1];
    unsigned* cand = hr + O_CAND;
    unsigned* hc   = hr + O_HC;
    unsigned* tiny = hr + O_TINY;
    if (cnt > CAP) { if (lane == 0) br[2] = (m1 == 0) ? 0u : SENT; return; }
    for (unsigned i = lane; i < cnt; i += 64) atomicAdd(&hc[cand[i] >> 24], 1u);
    unsigned hh[4];
#pragma unroll
    for (int i = 0; i < 4; ++i) hh[i] = hc[4 * lane + i];
    const unsigned s4 = hh[0] + hh[1] + hh[2] + hh[3];
    unsigned run2 = wscan_incl(s4) - s4;
    unsigned packed2 = 0;
#pragma unroll
    for (int i = 0; i < 4; ++i) {
        if (fromTop) {
            const unsigned suf = cnt - run2 - hh[i];
            if (suf < m1 && m1 <= suf + hh[i])
                packed2 = ((unsigned)(4 * lane + i) << 16) | (m1 - suf);
        } else {
            if (run2 < m1 && m1 <= run2 + hh[i])
                packed2 = ((unsigned)(4 * lane + i) << 16) | (m1 - run2);
        }
        run2 += hh[i];
    }
    packed2 = bcast_first(packed2, packed2);
    if (packed2 == 0) { if (lane == 0) br[2] = 0u; return; }  // m1==0 sentinel
    const unsigned b2 = packed2 >> 16;
    const unsigned m2 = packed2 & 0xFFFFu;
    unsigned tc = 0;
    for (unsigned i = lane; i < cnt; i += 64) tc += ((cand[i] >> 24) == b2);
    const unsigned tincl = wscan_incl(tc);
    const unsigned c2 = __shfl((int)tincl, 63, 64);
    if (c2 > CAP2) { if (lane == 0) br[2] = SENT; return; }
    unsigned tpos = tincl - tc;
    for (unsigned i = lane; i < cnt; i += 64) {
        const unsigned cw = cand[i];
        if ((cw >> 24) == b2) tiny[tpos++] = cw;
    }
    unsigned hitf = 0, resv = 0;
    if ((unsigned)lane < c2) {
        const unsigned ci = tiny[lane];
        const unsigned di = fromTop ? (ci ^ 0xFFFu) : ci;
        unsigned r = 1;
        for (unsigned j = 0; j < c2; ++j) {
            const unsigned dj = fromTop ? (tiny[j] ^ 0xFFFu) : tiny[j];
            if (fromTop ? (dj > di) : (dj < di)) r++;
        }
        if (r == m2) { hitf = 1; resv = ci; }
    }
    resv = bcast_first(hitf, resv);
    if (lane == 0) br[2] = resv;
}

// Pathological fallback: bin-filtered counting rank over global row.
template <bool fromTop>
__device__ void block_fallback(const unsigned* __restrict__ gx, unsigned* br) {
    const unsigned b0 = br[0], m1 = br[1];
    const int t = threadIdx.x;
    for (int j = t; j < HW; j += NT) {
        const unsigned k = gx[j] & M31;
        if ((k >> 20) != b0) continue;
        unsigned Ci = ((k & 0xFFFFFu) << 12) | (unsigned)j;
        if (fromTop) Ci ^= 0xFFFu;
        unsigned r = 1;
        for (int j2 = 0; j2 < HW; ++j2) {
            const unsigned k2 = gx[j2] & M31;
            if ((k2 >> 20) != b0) continue;
            unsigned Cj = ((k2 & 0xFFFFFu) << 12) | (unsigned)j2;
            if (fromTop) Cj ^= 0xFFFu;
            if (fromTop ? (Cj > Ci) : (Cj < Ci)) r++;
        }
        if (r == m1) br[2] = ((k & 0xFFFFFu) << 12) | (unsigned)j;
    }
}

extern "C" __global__ void __launch_bounds__(NT, 6)
topk_kernel(const float* __restrict__ x, float* __restrict__ out) {
    __shared__ unsigned s_h[1024];   // 4096 B: packed hist -> cand/hc/tiny
    __shared__ unsigned s_warp[2];
    __shared__ unsigned s_b[4];      // [0]=bin [1]=m1 [2]=result [3]=counter

    const int t = threadIdx.x;
    const int lane = t & 63;
    const int wid = t >> 6;
    const size_t row = blockIdx.x;
    const uint4* __restrict__ xin = (const uint4*)(x + row * HW);
    uint4* __restrict__ xo = (uint4*)(out + row * HW);
    const unsigned* __restrict__ gx = (const unsigned*)xin;
    const uint4 z4 = make_uint4(0u, 0u, 0u, 0u);

    // load row into registers; asm fence blocks rematerialization-as-reload
    uint4 v[6];
#pragma unroll
    for (int i = 0; i < 6; ++i) v[i] = xin[t + NT * i];
    uint4 vt = (t < 16) ? xin[768 + t] : z4;
#pragma unroll
    for (int i = 0; i < 6; ++i)
        asm volatile("" : "+v"(v[i].x), "+v"(v[i].y), "+v"(v[i].z), "+v"(v[i].w));
    asm volatile("" : "+v"(vt.x), "+v"(vt.y), "+v"(vt.z), "+v"(vt.w));

    // P0: clear hist (256 uint4 = 1024 words)
    ((uint4*)s_h)[t] = z4;
    ((uint4*)s_h)[t + NT] = z4;
    __syncthreads();

    // P1: 2048-bin packed-u16 histogram from registers (abs bits 30:20)
#pragma unroll
    for (int i = 0; i < 6; ++i) {
        hadd(s_h, (v[i].x & M31) >> 20); hadd(s_h, (v[i].y & M31) >> 20);
        hadd(s_h, (v[i].z & M31) >> 20); hadd(s_h, (v[i].w & M31) >> 20);
    }
    if (t < 16) {
        hadd(s_h, (vt.x & M31) >> 20); hadd(s_h, (vt.y & M31) >> 20);
        hadd(s_h, (vt.z & M31) >> 20); hadd(s_h, (vt.w & M31) >> 20);
    }
    __syncthreads();

    // P2: pull packed counts (thread t owns bins 16t..16t+15); wave sums
    const uint4 w0 = ((const uint4*)s_h)[2 * t];
    const uint4 w1 = ((const uint4*)s_h)[2 * t + 1];
    unsigned cpk[8] = {w0.x, w0.y, w0.z, w0.w, w1.x, w1.y, w1.z, w1.w};
    unsigned ssum = 0;
#pragma unroll
    for (int j = 0; j < 8; ++j) ssum += (cpk[j] & 0xFFFFu) + (cpk[j] >> 16);
    const unsigned Si = wscan_incl(ssum);
    if (lane == 63) s_warp[wid] = Si;
    __syncthreads();

    // P3: base; locate A (register CDF); zero counter; clear hc
    const unsigned base = Si - ssum + (wid ? s_warp[0] : 0u);
    {
        unsigned run = base;
#pragma unroll
        for (int j = 0; j < 8; ++j) {
            const unsigned lo = cpk[j] & 0xFFFFu, hi = cpk[j] >> 16;
            unsigned suf = HW - run - lo;
            if (suf < KSEL && KSEL <= suf + lo) { s_b[0] = 16u * t + 2u * j; s_b[1] = KSEL - suf; }
            run += lo;
            suf = HW - run - hi;
            if (suf < KSEL && KSEL <= suf + hi) { s_b[0] = 16u * t + 2u * j + 1u; s_b[1] = KSEL - suf; }
            run += hi;
        }
    }
    if (t == 0) s_b[3] = 0;
    s_h[O_HC + t] = 0; s_h[O_HC + t + NT] = 0;
    __syncthreads();

    // P4: compact A from registers
    auto compact_regs = [&](unsigned b0) {
        auto cput = [&](unsigned wv, unsigned idx) {
            const unsigned k = wv & M31;
            if ((k >> 20) == b0) {
                const unsigned p = atomicAdd(&s_b[3], 1u);
                if (p < CAP) s_h[O_CAND + p] = ((k & 0xFFFFFu) << 12) | idx;
            }
        };
#pragma unroll
        for (int i = 0; i < 6; ++i) {
            const unsigned i0 = 4u * (unsigned)(t + NT * i);
            cput(v[i].x, i0); cput(v[i].y, i0 + 1u);
            cput(v[i].z, i0 + 2u); cput(v[i].w, i0 + 3u);
        }
        if (t < 16) {
            const unsigned i0 = 4u * (unsigned)(768 + t);
            cput(vt.x, i0); cput(vt.y, i0 + 1u);
            cput(vt.z, i0 + 2u); cput(vt.w, i0 + 3u);
        }
    };
    compact_regs(s_b[0]);
    __syncthreads();

    // P5: wave0 finish A
    if (wid == 0) wave_finish<true>(s_h, s_b);
    __syncthreads();

    unsigned compA = s_b[2];
    if (compA == SENT) { block_fallback<true>(gx, s_b); __syncthreads(); compA = s_b[2]; }
    const unsigned tIdx = compA & 0xFFFu;

    // P6: locate B; zero counter; clear hc; keep-nothing sentinel
    {
        unsigned run = base;
#pragma unroll
        for (int j = 0; j < 8; ++j) {
            const unsigned lo = cpk[j] & 0xFFFFu, hi = cpk[j] >> 16;
            if (run < tIdx && tIdx <= run + lo) { s_b[0] = 16u * t + 2u * j; s_b[1] = tIdx - run; }
            run += lo;
            if (run < tIdx && tIdx <= run + hi) { s_b[0] = 16u * t + 2u * j + 1u; s_b[1] = tIdx - run; }
            run += hi;
        }
    }
    if (t == 0) {
        s_b[3] = 0;
        if (tIdx == 0) { s_b[0] = 0; s_b[1] = 0; }   // keep-nothing (benign)
    }
    s_h[O_HC + t] = 0; s_h[O_HC + t + NT] = 0;
    __syncthreads();

    // P7: compact B from registers
    const unsigned b0B = s_b[0];
    compact_regs(b0B);
    __syncthreads();

    // P8: wave0 finish B
    if (wid == 0) wave_finish<false>(s_h, s_b);
    __syncthreads();

    unsigned compB = s_b[2];
    if (compB == SENT) { block_fallback<false>(gx, s_b); __syncthreads(); compB = s_b[2]; }
    const unsigned KB = (b0B << 20) | (compB >> 12);
    const unsigned eB = compB & 0xFFFu;

    // P9: mask + store from registers
    {
        auto msk = [&](unsigned wv, unsigned idx) -> unsigned {
            const unsigned k = wv & M31;
            return (k < KB || (k == KB && idx <= eB)) ? wv : 0u;
        };
#pragma unroll
        for (int i = 0; i < 6; ++i) {
            const unsigned i0 = 4u * (unsigned)(t + NT * i);
            uint4 o = v[i];
            o.x = msk(o.x, i0); o.y = msk(o.y, i0 + 1u);
            o.z = msk(o.z, i0 + 2u); o.w = msk(o.w, i0 + 3u);
            xo[t + NT * i] = o;
        }
        if (t < 16) {
            const unsigned i0 = 4u * (unsigned)(768 + t);
            uint4 o = vt;
            o.x = msk(o.x, i0); o.y = msk(o.y, i0 + 1u);
            o.z = msk(o.z, i0 + 2u); o.w = msk(o.w, i0 + 3u);
            xo[768 + t] = o;
        }
    }
}

extern "C" void kernel_launch(void* const* d_in, const int* in_sizes, int n_in,
                              void* d_out, int out_size, void* d_ws, size_t ws_size,
                              hipStream_t stream) {
    const float* x = (const float*)d_in[0];
    float* out = (float*)d_out;
    const int rows = in_sizes[0] / HW;          // 8192
    topk_kernel<<<dim3(rows), dim3(NT), 0, stream>>>(x, out);
}